// Round 1
// baseline (1133.764 us; speedup 1.0000x reference)
//
#include <hip/hip_runtime.h>
#include <math.h>

namespace {

constexpr int B_ = 2;
constexpr int T_ = 2048;
constexpr int C_ = 1024;
constexpr int H_ = 16;
constexpr int HD_ = 64;
constexpr int HALF_ = 32;
constexpr int NQ_ = 3 * C_;   // 3072
constexpr int M_ = B_ * T_;   // 4096
constexpr float SCALE_ = 0.125f; // 64^-0.5

// ---------------------------------------------------------------- RoPE tables
// cos_t/sin_t: [T][HALF] (one entry per pair, reference repeats it for both)
__global__ void rope_tab_k(float* __restrict__ cos_t, float* __restrict__ sin_t) {
    int idx = blockIdx.x * 256 + threadIdx.x;
    if (idx >= T_ * HALF_) return;
    int t = idx >> 5;
    int i = idx & (HALF_ - 1);
    float inv = powf(10000.0f, -(float)i / (float)HALF_);
    float ang = (float)t * inv;
    cos_t[idx] = cosf(ang);
    sin_t[idx] = sinf(ang);
}

// ---------------------------------------------------------------- QKV GEMM + RoPE
// x:(M,C) row-major; w:(NQ,C) row-major; out = x @ w^T, col n -> sec=n/1024,
// h=(n%1024)/64, d=n%64. RoPE applied to sec 0,1. Write q/k/v as [B,H,T,hd].
constexpr int BM = 64, BN = 64, BK = 32;

__global__ __launch_bounds__(256)
void qkv_rope_k(const float* __restrict__ x, const float* __restrict__ w,
                const float* __restrict__ cos_t, const float* __restrict__ sin_t,
                float* __restrict__ qb, float* __restrict__ kb, float* __restrict__ vb) {
    __shared__ float As[BK][BM];   // [k][m] transposed for float4 m-reads
    __shared__ float Bs[BK][BN];
    const int tid = threadIdx.x;
    const int m0 = blockIdx.y * BM;
    const int n0 = blockIdx.x * BN;
    const int tx = tid & 15, ty = tid >> 4;
    const int lm = tid & 63;
    const int lk = (tid >> 6) << 3;   // 0,8,16,24
    const float* __restrict__ xrow = x + (size_t)(m0 + lm) * C_;
    const float* __restrict__ wrow = w + (size_t)(n0 + lm) * C_;
    float acc[4][4] = {};
    for (int k0 = 0; k0 < C_; k0 += BK) {
        float4 a0 = *(const float4*)(xrow + k0 + lk);
        float4 a1 = *(const float4*)(xrow + k0 + lk + 4);
        float4 b0 = *(const float4*)(wrow + k0 + lk);
        float4 b1 = *(const float4*)(wrow + k0 + lk + 4);
        As[lk + 0][lm] = a0.x; As[lk + 1][lm] = a0.y; As[lk + 2][lm] = a0.z; As[lk + 3][lm] = a0.w;
        As[lk + 4][lm] = a1.x; As[lk + 5][lm] = a1.y; As[lk + 6][lm] = a1.z; As[lk + 7][lm] = a1.w;
        Bs[lk + 0][lm] = b0.x; Bs[lk + 1][lm] = b0.y; Bs[lk + 2][lm] = b0.z; Bs[lk + 3][lm] = b0.w;
        Bs[lk + 4][lm] = b1.x; Bs[lk + 5][lm] = b1.y; Bs[lk + 6][lm] = b1.z; Bs[lk + 7][lm] = b1.w;
        __syncthreads();
#pragma unroll
        for (int kk = 0; kk < BK; ++kk) {
            float4 av = *(const float4*)&As[kk][ty << 2];
            float4 bv = *(const float4*)&Bs[kk][tx << 2];
            float a[4] = {av.x, av.y, av.z, av.w};
            float b[4] = {bv.x, bv.y, bv.z, bv.w};
#pragma unroll
            for (int i = 0; i < 4; ++i)
#pragma unroll
                for (int j = 0; j < 4; ++j) acc[i][j] = fmaf(a[i], b[j], acc[i][j]);
        }
        __syncthreads();
    }
    // epilogue: whole block is within one (sec, h, b) since BN=64 | 1024, BM=64 | 2048
    const int sec = n0 >> 10;
    const int h = (n0 & 1023) >> 6;
    const int bb = m0 / T_;
    const int tbase = m0 % T_;
    float* __restrict__ dst = (sec == 0) ? qb : (sec == 1) ? kb : vb;
#pragma unroll
    for (int i = 0; i < 4; ++i) {
        int t = tbase + (ty << 2) + i;
        size_t rowbase = ((size_t)(bb * H_ + h) * T_ + t) * HD_;
#pragma unroll
        for (int jp = 0; jp < 4; jp += 2) {
            int d = (tx << 2) + jp;   // even
            float e = acc[i][jp], o = acc[i][jp + 1];
            float re, ro;
            if (sec < 2) {
                float c = cos_t[t * HALF_ + (d >> 1)];
                float s = sin_t[t * HALF_ + (d >> 1)];
                re = e * c - o * s;
                ro = o * c + e * s;
            } else {
                re = e; ro = o;
            }
            *(float2*)(dst + rowbase + d) = make_float2(re, ro);
        }
    }
}

// ---------------------------------------------------------------- flash attention
// one block: 64 q-rows of one (b,h); iterate causal K/V 64-tiles
__global__ __launch_bounds__(256)
void flash_k(const float* __restrict__ qb, const float* __restrict__ kb,
             const float* __restrict__ vb, float* __restrict__ att) {
    __shared__ float Qs[HD_][64];   // [d][row]
    __shared__ float Ks[HD_][64];   // [d][row]
    __shared__ float Vs[64][HD_];   // [row][d]
    __shared__ float Ps[64][64];    // [qrow][krow]
    const int qi = blockIdx.x;      // q tile
    const int bh = blockIdx.y;      // b*H+h
    const int bb = bh / H_, h = bh % H_;
    const int tid = threadIdx.x;
    const int tx = tid & 15, ty = tid >> 4;
    const int lr = tid & 63;        // loader row
    const int lc = tid >> 6;        // loader chunk of 16
    // load Q transposed
    {
        const float* src = qb + ((size_t)bh * T_ + qi * 64 + lr) * HD_ + lc * 16;
#pragma unroll
        for (int u = 0; u < 16; u += 4) {
            float4 v4 = *(const float4*)(src + u);
            Qs[lc * 16 + u + 0][lr] = v4.x;
            Qs[lc * 16 + u + 1][lr] = v4.y;
            Qs[lc * 16 + u + 2][lr] = v4.z;
            Qs[lc * 16 + u + 3][lr] = v4.w;
        }
    }
    float m_run[4] = {-INFINITY, -INFINITY, -INFINITY, -INFINITY};
    float l_run[4] = {};
    float acc_o[4][4] = {};
    for (int kt = 0; kt <= qi; ++kt) {
        __syncthreads();   // Qs ready / prev PV done
        {
            const float* ksrc = kb + ((size_t)bh * T_ + kt * 64 + lr) * HD_ + lc * 16;
            const float* vsrc = vb + ((size_t)bh * T_ + kt * 64 + lr) * HD_ + lc * 16;
#pragma unroll
            for (int u = 0; u < 16; u += 4) {
                float4 v4 = *(const float4*)(ksrc + u);
                Ks[lc * 16 + u + 0][lr] = v4.x;
                Ks[lc * 16 + u + 1][lr] = v4.y;
                Ks[lc * 16 + u + 2][lr] = v4.z;
                Ks[lc * 16 + u + 3][lr] = v4.w;
                *(float4*)&Vs[lr][lc * 16 + u] = *(const float4*)(vsrc + u);
            }
        }
        __syncthreads();   // tiles ready
        float sacc[4][4] = {};
#pragma unroll 16
        for (int d = 0; d < HD_; ++d) {
            float4 av = *(const float4*)&Qs[d][ty << 2];
            float4 bv = *(const float4*)&Ks[d][tx << 2];
            float a[4] = {av.x, av.y, av.z, av.w};
            float b[4] = {bv.x, bv.y, bv.z, bv.w};
#pragma unroll
            for (int i = 0; i < 4; ++i)
#pragma unroll
                for (int j = 0; j < 4; ++j) sacc[i][j] = fmaf(a[i], b[j], sacc[i][j]);
        }
        const bool diag = (kt == qi);
#pragma unroll
        for (int i = 0; i < 4; ++i) {
            float s[4];
#pragma unroll
            for (int j = 0; j < 4; ++j) {
                s[j] = sacc[i][j] * SCALE_;
                if (diag && ((tx << 2) + j > (ty << 2) + i)) s[j] = -INFINITY;
            }
            float mx = fmaxf(fmaxf(s[0], s[1]), fmaxf(s[2], s[3]));
            mx = fmaxf(mx, __shfl_xor(mx, 1));
            mx = fmaxf(mx, __shfl_xor(mx, 2));
            mx = fmaxf(mx, __shfl_xor(mx, 4));
            mx = fmaxf(mx, __shfl_xor(mx, 8));
            float mnew = fmaxf(m_run[i], mx);
            float alpha = expf(m_run[i] - mnew);
            float p[4], sum = 0.f;
#pragma unroll
            for (int j = 0; j < 4; ++j) { p[j] = expf(s[j] - mnew); sum += p[j]; }
            sum += __shfl_xor(sum, 1);
            sum += __shfl_xor(sum, 2);
            sum += __shfl_xor(sum, 4);
            sum += __shfl_xor(sum, 8);
            l_run[i] = l_run[i] * alpha + sum;
            m_run[i] = mnew;
#pragma unroll
            for (int j = 0; j < 4; ++j) acc_o[i][j] *= alpha;
            *(float4*)&Ps[(ty << 2) + i][tx << 2] = make_float4(p[0], p[1], p[2], p[3]);
        }
        __syncthreads();   // Ps ready
#pragma unroll 4
        for (int n4 = 0; n4 < 64; n4 += 4) {
            float pa[4][4];
#pragma unroll
            for (int i = 0; i < 4; ++i) {
                float4 v4 = *(const float4*)&Ps[(ty << 2) + i][n4];
                pa[i][0] = v4.x; pa[i][1] = v4.y; pa[i][2] = v4.z; pa[i][3] = v4.w;
            }
#pragma unroll
            for (int c = 0; c < 4; ++c) {
                float4 bv = *(const float4*)&Vs[n4 + c][tx << 2];
                float b[4] = {bv.x, bv.y, bv.z, bv.w};
#pragma unroll
                for (int i = 0; i < 4; ++i)
#pragma unroll
                    for (int j = 0; j < 4; ++j)
                        acc_o[i][j] = fmaf(pa[i][c], b[j], acc_o[i][j]);
            }
        }
    }
    // write out: att[b][t][h*64+d]
#pragma unroll
    for (int i = 0; i < 4; ++i) {
        float inv = 1.0f / l_run[i];
        int qrow = qi * 64 + (ty << 2) + i;
        float4 o = make_float4(acc_o[i][0] * inv, acc_o[i][1] * inv,
                               acc_o[i][2] * inv, acc_o[i][3] * inv);
        *(float4*)(att + ((size_t)bb * T_ + qrow) * C_ + h * HD_ + (tx << 2)) = o;
    }
}

// ---------------------------------------------------------------- out proj GEMM + bias
__global__ __launch_bounds__(256)
void proj_k(const float* __restrict__ a, const float* __restrict__ w,
            const float* __restrict__ bias, float* __restrict__ out) {
    __shared__ float As[BK][BM];
    __shared__ float Bs[BK][BN];
    const int tid = threadIdx.x;
    const int m0 = blockIdx.y * BM;
    const int n0 = blockIdx.x * BN;
    const int tx = tid & 15, ty = tid >> 4;
    const int lm = tid & 63;
    const int lk = (tid >> 6) << 3;
    const float* __restrict__ arow = a + (size_t)(m0 + lm) * C_;
    const float* __restrict__ wrow = w + (size_t)(n0 + lm) * C_;
    float acc[4][4] = {};
    for (int k0 = 0; k0 < C_; k0 += BK) {
        float4 a0 = *(const float4*)(arow + k0 + lk);
        float4 a1 = *(const float4*)(arow + k0 + lk + 4);
        float4 b0 = *(const float4*)(wrow + k0 + lk);
        float4 b1 = *(const float4*)(wrow + k0 + lk + 4);
        As[lk + 0][lm] = a0.x; As[lk + 1][lm] = a0.y; As[lk + 2][lm] = a0.z; As[lk + 3][lm] = a0.w;
        As[lk + 4][lm] = a1.x; As[lk + 5][lm] = a1.y; As[lk + 6][lm] = a1.z; As[lk + 7][lm] = a1.w;
        Bs[lk + 0][lm] = b0.x; Bs[lk + 1][lm] = b0.y; Bs[lk + 2][lm] = b0.z; Bs[lk + 3][lm] = b0.w;
        Bs[lk + 4][lm] = b1.x; Bs[lk + 5][lm] = b1.y; Bs[lk + 6][lm] = b1.z; Bs[lk + 7][lm] = b1.w;
        __syncthreads();
#pragma unroll
        for (int kk = 0; kk < BK; ++kk) {
            float4 av = *(const float4*)&As[kk][ty << 2];
            float4 bv = *(const float4*)&Bs[kk][tx << 2];
            float a2[4] = {av.x, av.y, av.z, av.w};
            float b2[4] = {bv.x, bv.y, bv.z, bv.w};
#pragma unroll
            for (int i = 0; i < 4; ++i)
#pragma unroll
                for (int j = 0; j < 4; ++j) acc[i][j] = fmaf(a2[i], b2[j], acc[i][j]);
        }
        __syncthreads();
    }
    float4 bv = *(const float4*)(bias + n0 + (tx << 2));
    float bj[4] = {bv.x, bv.y, bv.z, bv.w};
#pragma unroll
    for (int i = 0; i < 4; ++i) {
        int gm = m0 + (ty << 2) + i;
        float4 o = make_float4(acc[i][0] + bj[0], acc[i][1] + bj[1],
                               acc[i][2] + bj[2], acc[i][3] + bj[3]);
        *(float4*)(out + (size_t)gm * C_ + n0 + (tx << 2)) = o;
    }
}

} // namespace

extern "C" void kernel_launch(void* const* d_in, const int* in_sizes, int n_in,
                              void* d_out, int out_size, void* d_ws, size_t ws_size,
                              hipStream_t stream) {
    const float* x     = (const float*)d_in[0];
    const float* w_qkv = (const float*)d_in[1];
    const float* w_out = (const float*)d_in[2];
    const float* b_out = (const float*)d_in[3];
    float* out = (float*)d_out;

    float* ws = (float*)d_ws;
    float* cos_t = ws;                               // T*HALF
    float* sin_t = cos_t + (size_t)T_ * HALF_;       // T*HALF
    float* qb    = sin_t + (size_t)T_ * HALF_;       // B*H*T*HD
    float* kb    = qb + (size_t)B_ * H_ * T_ * HD_;
    float* vb    = kb + (size_t)B_ * H_ * T_ * HD_;
    float* att   = vb + (size_t)B_ * H_ * T_ * HD_;  // M*C

    rope_tab_k<<<(T_ * HALF_ + 255) / 256, 256, 0, stream>>>(cos_t, sin_t);
    qkv_rope_k<<<dim3(NQ_ / BN, M_ / BM), 256, 0, stream>>>(x, w_qkv, cos_t, sin_t, qb, kb, vb);
    flash_k<<<dim3(T_ / 64, B_ * H_), 256, 0, stream>>>(qb, kb, vb, att);
    proj_k<<<dim3(C_ / BN, M_ / BM), 256, 0, stream>>>(att, w_out, b_out, out);
}

// Round 3
// 257.700 us; speedup vs baseline: 4.3995x; 4.3995x over previous
//
#include <hip/hip_runtime.h>
#include <math.h>

namespace {

typedef __attribute__((ext_vector_type(8))) short s16x8;
typedef __attribute__((ext_vector_type(4))) float f32x4;
typedef unsigned int u32;
typedef unsigned short u16;

constexpr int B_ = 2;
constexpr int T_ = 2048;
constexpr int C_ = 1024;
constexpr int H_ = 16;
constexpr float L2E = 1.44269504088896340736f;

__device__ inline u16 f2bf(float x) {
    __bf16 h = (__bf16)x;
    return __builtin_bit_cast(u16, h);
}
__device__ inline u32 packbf2(float a, float b) {
    return (u32)f2bf(a) | ((u32)f2bf(b) << 16);
}
__device__ inline void gload_lds16(const void* g, void* lds) {
    __builtin_amdgcn_global_load_lds(
        (const __attribute__((address_space(1))) unsigned int*)g,
        (__attribute__((address_space(3))) unsigned int*)lds, 16, 0, 0);
}

// ---------------------------------------------------------------- RoPE table
// cs[t][i] = {cos, sin}, i in [0,32)
__global__ __launch_bounds__(256) void tab_k(float2* __restrict__ cs) {
    int idx = blockIdx.x * 256 + threadIdx.x;   // 65536
    int t = idx >> 5, i = idx & 31;
    float inv = 1.0f / powf(10000.0f, (float)i / 32.0f);
    float ang = (float)t * inv;
    cs[idx] = make_float2(cosf(ang), sinf(ang));
}

// ---------------------------------------------------------------- f32 -> bf16 convert
// x (1048576 float4) | w_qkv (786432) | w_out (262144)
__global__ __launch_bounds__(256)
void cvt_k(const float4* __restrict__ x, const float4* __restrict__ wq,
           const float4* __restrict__ wo, uint2* __restrict__ xb,
           uint2* __restrict__ wqb, uint2* __restrict__ wob) {
    int i = blockIdx.x * 256 + threadIdx.x;   // 2097152 total
    const float4* s;
    uint2* d;
    int j;
    if (i < 1048576) { s = x; d = xb; j = i; }
    else if (i < 1048576 + 786432) { s = wq; d = wqb; j = i - 1048576; }
    else { s = wo; d = wob; j = i - (1048576 + 786432); }
    float4 v = s[j];
    d[j] = make_uint2(packbf2(v.x, v.y), packbf2(v.z, v.w));
}

// ---------------------------------------------------------------- QKV MFMA GEMM + RoPE
// 128x128 tile, BK=32. A = xb[M=4096][1024], B^T = wqb[N=3072][1024].
// Epilogue: sec0 -> qb (rope, *0.125), sec1 -> kb (rope), sec2 -> vt (transposed).
__global__ __launch_bounds__(256)
void qkv_mfma_k(const u16* __restrict__ xb, const u16* __restrict__ wqb,
                const float2* __restrict__ cs, u16* __restrict__ qb,
                u16* __restrict__ kb, u16* __restrict__ vt) {
    __shared__ char lds[16384];       // A 8KB | B 8KB, rows 64B, swizzle ^((row&3)<<4)
    const int tid = threadIdx.x;
    const int w = tid >> 6, lane = tid & 63;
    const int c = lane & 15, g = lane >> 4;
    const int n0 = blockIdx.x * 128, m0 = blockIdx.y * 128;
    const int wr = w >> 1, wc = w & 1;

    f32x4 acc[4][4];
#pragma unroll
    for (int i = 0; i < 4; ++i)
#pragma unroll
        for (int j = 0; j < 4; ++j) acc[i][j] = (f32x4){0.f, 0.f, 0.f, 0.f};

    const u16* Ab = xb + (size_t)m0 * C_;
    const u16* Bb = wqb + (size_t)n0 * C_;
    const int srow = tid >> 2, sslot = tid & 3;

    for (int k0 = 0; k0 < C_; k0 += 32) {
        __syncthreads();
#pragma unroll
        for (int call = 0; call < 2; ++call) {
            int r = call * 64 + srow;
            int ds = sslot ^ (r & 3);
            gload_lds16(Ab + (size_t)r * C_ + k0 + ds * 8, lds + call * 4096 + w * 1024);
            gload_lds16(Bb + (size_t)r * C_ + k0 + ds * 8, lds + 8192 + call * 4096 + w * 1024);
        }
        __syncthreads();
        s16x8 aF[4], bF[4];
#pragma unroll
        for (int mf = 0; mf < 4; ++mf) {
            int row = wr * 64 + mf * 16 + c;
            aF[mf] = *(const s16x8*)(lds + row * 64 + ((g ^ (row & 3)) * 16));
        }
#pragma unroll
        for (int nf = 0; nf < 4; ++nf) {
            int row = wc * 64 + nf * 16 + c;
            bF[nf] = *(const s16x8*)(lds + 8192 + row * 64 + ((g ^ (row & 3)) * 16));
        }
#pragma unroll
        for (int mf = 0; mf < 4; ++mf)
#pragma unroll
            for (int nf = 0; nf < 4; ++nf)
                acc[mf][nf] = __builtin_amdgcn_mfma_f32_16x16x32_bf16(aF[mf], bF[nf], acc[mf][nf], 0, 0, 0);
    }

    // epilogue
    const int sec = n0 >> 10;
    const int h = ((n0 & 1023) >> 6) + wc;
    const int b = m0 >> 11;
    const int t0w = (m0 & 2047) + wr * 64;
    const int bh = b * H_ + h;
    if (sec < 2) {
        u16* dst = (sec == 0) ? qb : kb;
        const float qs = (sec == 0) ? 0.125f : 1.0f;
#pragma unroll
        for (int nf = 0; nf < 4; ++nf) {
            int d = nf * 16 + c;
            int ibase = nf * 8 + (c >> 1);
#pragma unroll
            for (int mf = 0; mf < 4; ++mf) {
#pragma unroll
                for (int r = 0; r < 4; ++r) {
                    int t = t0w + mf * 16 + g * 4 + r;
                    float own = acc[mf][nf][r];
                    float partner = __shfl_xor(own, 1);
                    float2 csv = cs[t * 32 + ibase];
                    float rot = (d & 1) ? (own * csv.x + partner * csv.y)
                                        : (own * csv.x - partner * csv.y);
                    rot *= qs;
                    float rothi = __shfl_xor(rot, 1);
                    if (!(d & 1))
                        *(u32*)(dst + ((size_t)bh * T_ + t) * 64 + d) = packbf2(rot, rothi);
                }
            }
        }
    } else {
#pragma unroll
        for (int nf = 0; nf < 4; ++nf) {
            int d = nf * 16 + c;
#pragma unroll
            for (int mf = 0; mf < 4; ++mf) {
                int tb = t0w + mf * 16 + g * 4;
                u32 lo = packbf2(acc[mf][nf][0], acc[mf][nf][1]);
                u32 hi = packbf2(acc[mf][nf][2], acc[mf][nf][3]);
                *(uint2*)(vt + ((size_t)bh * 64 + d) * T_ + tb) = make_uint2(lo, hi);
            }
        }
    }
}

// ---------------------------------------------------------------- flash attention (bf16 MFMA)
// block: 128 q-rows of one (b,h); 4 waves x 32 rows. KV tiles of 64.
// S^T = mfma(K, Q) so softmax is reg-local + 2 shuffles; P -> LDS -> PV.
__global__ __launch_bounds__(256)
void flash_mfma_k(const u16* __restrict__ qb, const u16* __restrict__ kb,
                  const u16* __restrict__ vt, u16* __restrict__ attb) {
    __shared__ char lds[49152];
    char* Qs = lds;                // 16KB: 128 rows x 128B, swz ^((row&7)<<4)
    char* Ks = lds + 16384;        // 8KB: 64 x 128B
    char* Vs = lds + 24576;        // 8KB: V^T tile, rows = d
    char* Ps = lds + 32768;        // 16KB: per-wave 4KB, 32 x 128B
    const int tid = threadIdx.x, w = tid >> 6, lane = tid & 63;
    const int c = lane & 15, g = lane >> 4;
    const int bh = blockIdx.x, qi = blockIdx.y;
    const int q0 = qi * 128, q0w = q0 + w * 32;
    const u16* Qg = qb + ((size_t)bh * T_ + q0) * 64;
    const u16* Kg = kb + (size_t)bh * T_ * 64;
    const u16* Vg = vt + (size_t)bh * 64 * T_;

    // stage Q (16KB, swizzled source)
#pragma unroll
    for (int call = 0; call < 4; ++call) {
        int row = call * 32 + (tid >> 3);
        int ds = (tid & 7) ^ (row & 7);
        gload_lds16(Qg + (size_t)row * 64 + ds * 8, Qs + call * 4096 + w * 1024);
    }
    __syncthreads();

    s16x8 bQ[2][2];
#pragma unroll
    for (int nf = 0; nf < 2; ++nf)
#pragma unroll
        for (int kc = 0; kc < 2; ++kc) {
            int row = w * 32 + nf * 16 + c;
            bQ[nf][kc] = *(const s16x8*)(Qs + row * 128 + (((kc * 4 + g) ^ (row & 7)) * 16));
        }

    float m_[2] = {-INFINITY, -INFINITY}, l_[2] = {0.f, 0.f};
    f32x4 accO[2][4];
#pragma unroll
    for (int i = 0; i < 2; ++i)
#pragma unroll
        for (int j = 0; j < 4; ++j) accO[i][j] = (f32x4){0.f, 0.f, 0.f, 0.f};

    const int nt = 2 * (qi + 1);
    for (int kt = 0; kt < nt; ++kt) {
        __syncthreads();
        {
            int row = tid >> 3, slot = tid & 7;
#pragma unroll
            for (int call = 0; call < 2; ++call) {
                int r = call * 32 + row;
                int ds = slot ^ (r & 7);
                gload_lds16(Kg + (size_t)(kt * 64 + r) * 64 + ds * 8, Ks + call * 4096 + w * 1024);
                gload_lds16(Vg + (size_t)r * T_ + kt * 64 + ds * 8, Vs + call * 4096 + w * 1024);
            }
        }
        __syncthreads();
        if (kt * 64 < q0w + 32) {
            // S^T = K . Q^T   (S^T frag: row=kv=(g*4+r)+16mf, col=qrow=c+16nf)
            f32x4 S[4][2];
#pragma unroll
            for (int mf = 0; mf < 4; ++mf)
#pragma unroll
                for (int nf = 0; nf < 2; ++nf) S[mf][nf] = (f32x4){0.f, 0.f, 0.f, 0.f};
            s16x8 aK[4][2];
#pragma unroll
            for (int mf = 0; mf < 4; ++mf)
#pragma unroll
                for (int kc = 0; kc < 2; ++kc) {
                    int row = mf * 16 + c;
                    aK[mf][kc] = *(const s16x8*)(Ks + row * 128 + (((kc * 4 + g) ^ (row & 7)) * 16));
                }
#pragma unroll
            for (int kc = 0; kc < 2; ++kc)
#pragma unroll
                for (int mf = 0; mf < 4; ++mf)
#pragma unroll
                    for (int nf = 0; nf < 2; ++nf)
                        S[mf][nf] = __builtin_amdgcn_mfma_f32_16x16x32_bf16(aK[mf][kc], bQ[nf][kc], S[mf][nf], 0, 0, 0);
            // causal mask
            if (kt * 64 + 63 > q0w) {
#pragma unroll
                for (int mf = 0; mf < 4; ++mf)
#pragma unroll
                    for (int nf = 0; nf < 2; ++nf)
#pragma unroll
                        for (int r = 0; r < 4; ++r) {
                            int kvg = kt * 64 + mf * 16 + g * 4 + r;
                            int qg = q0w + nf * 16 + c;
                            if (kvg > qg) S[mf][nf][r] = -INFINITY;
                        }
            }
            // online softmax (q was pre-scaled by 0.125)
            float alpha[2];
#pragma unroll
            for (int nf = 0; nf < 2; ++nf) {
                float mx = -INFINITY;
#pragma unroll
                for (int mf = 0; mf < 4; ++mf)
#pragma unroll
                    for (int r = 0; r < 4; ++r) mx = fmaxf(mx, S[mf][nf][r]);
                mx = fmaxf(mx, __shfl_xor(mx, 16));
                mx = fmaxf(mx, __shfl_xor(mx, 32));
                float mnew = fmaxf(m_[nf], mx);
                alpha[nf] = exp2f((m_[nf] - mnew) * L2E);
                float sum = 0.f;
#pragma unroll
                for (int mf = 0; mf < 4; ++mf)
#pragma unroll
                    for (int r = 0; r < 4; ++r) {
                        float p = exp2f((S[mf][nf][r] - mnew) * L2E);
                        S[mf][nf][r] = p;
                        sum += p;
                    }
                sum += __shfl_xor(sum, 16);
                sum += __shfl_xor(sum, 32);
                l_[nf] = l_[nf] * alpha[nf] + sum;
                m_[nf] = mnew;
            }
            // rescale accO (row = qrow = 16mi + 4g + r)
#pragma unroll
            for (int mi = 0; mi < 2; ++mi)
#pragma unroll
                for (int r = 0; r < 4; ++r) {
                    float a = __shfl(alpha[mi], g * 4 + r);
#pragma unroll
                    for (int nd = 0; nd < 4; ++nd) accO[mi][nd][r] *= a;
                }
            // P -> LDS (P[qrow][kv], swizzled)
#pragma unroll
            for (int nf = 0; nf < 2; ++nf) {
                int prow = nf * 16 + c;
#pragma unroll
                for (int mf = 0; mf < 4; ++mf)
#pragma unroll
                    for (int p2 = 0; p2 < 2; ++p2) {
                        u32 v = packbf2(S[mf][nf][2 * p2], S[mf][nf][2 * p2 + 1]);
                        int off = (mf * 16 + g * 4 + p2 * 2) * 2;
                        *(u32*)(Ps + w * 4096 + prow * 128 + (off ^ ((prow & 7) << 4))) = v;
                    }
            }
            // order the u32 P-stores before the s16x8 P-loads (TBAA would
            // otherwise allow the ds_read to be hoisted above the ds_write)
            __threadfence_block();
            // PV: O += P . V
            s16x8 aP[2][2], bV[4][2];
#pragma unroll
            for (int mi = 0; mi < 2; ++mi)
#pragma unroll
                for (int kc = 0; kc < 2; ++kc) {
                    int row = mi * 16 + c;
                    aP[mi][kc] = *(const s16x8*)(Ps + w * 4096 + row * 128 + (((kc * 4 + g) ^ (row & 7)) * 16));
                }
#pragma unroll
            for (int nd = 0; nd < 4; ++nd)
#pragma unroll
                for (int kc = 0; kc < 2; ++kc) {
                    int row = nd * 16 + c;
                    bV[nd][kc] = *(const s16x8*)(Vs + row * 128 + (((kc * 4 + g) ^ (row & 7)) * 16));
                }
#pragma unroll
            for (int kc = 0; kc < 2; ++kc)
#pragma unroll
                for (int mi = 0; mi < 2; ++mi)
#pragma unroll
                    for (int nd = 0; nd < 4; ++nd)
                        accO[mi][nd] = __builtin_amdgcn_mfma_f32_16x16x32_bf16(aP[mi][kc], bV[nd][kc], accO[mi][nd], 0, 0, 0);
        }
    }
    // epilogue: attb[b*T + t][h*64 + d]
    const int hh = bh & 15;
    const int bb = bh >> 4;
#pragma unroll
    for (int mi = 0; mi < 2; ++mi)
#pragma unroll
        for (int r = 0; r < 4; ++r) {
            float linv = 1.0f / __shfl(l_[mi], g * 4 + r);
            int t = q0w + mi * 16 + g * 4 + r;
            size_t rowb = ((size_t)bb * T_ + t) * C_ + hh * 64;
#pragma unroll
            for (int nd = 0; nd < 4; ++nd)
                attb[rowb + nd * 16 + c] = f2bf(accO[mi][nd][r] * linv);
        }
}

// ---------------------------------------------------------------- out-proj MFMA GEMM + bias
__global__ __launch_bounds__(256)
void proj_mfma_k(const u16* __restrict__ attb, const u16* __restrict__ wob,
                 const float* __restrict__ bias, float* __restrict__ out) {
    __shared__ char lds[16384];
    const int tid = threadIdx.x;
    const int w = tid >> 6, lane = tid & 63;
    const int c = lane & 15, g = lane >> 4;
    const int n0 = blockIdx.x * 128, m0 = blockIdx.y * 128;
    const int wr = w >> 1, wc = w & 1;

    f32x4 acc[4][4];
#pragma unroll
    for (int i = 0; i < 4; ++i)
#pragma unroll
        for (int j = 0; j < 4; ++j) acc[i][j] = (f32x4){0.f, 0.f, 0.f, 0.f};

    const u16* Ab = attb + (size_t)m0 * C_;
    const u16* Bb = wob + (size_t)n0 * C_;
    const int srow = tid >> 2, sslot = tid & 3;

    for (int k0 = 0; k0 < C_; k0 += 32) {
        __syncthreads();
#pragma unroll
        for (int call = 0; call < 2; ++call) {
            int r = call * 64 + srow;
            int ds = sslot ^ (r & 3);
            gload_lds16(Ab + (size_t)r * C_ + k0 + ds * 8, lds + call * 4096 + w * 1024);
            gload_lds16(Bb + (size_t)r * C_ + k0 + ds * 8, lds + 8192 + call * 4096 + w * 1024);
        }
        __syncthreads();
        s16x8 aF[4], bF[4];
#pragma unroll
        for (int mf = 0; mf < 4; ++mf) {
            int row = wr * 64 + mf * 16 + c;
            aF[mf] = *(const s16x8*)(lds + row * 64 + ((g ^ (row & 3)) * 16));
        }
#pragma unroll
        for (int nf = 0; nf < 4; ++nf) {
            int row = wc * 64 + nf * 16 + c;
            bF[nf] = *(const s16x8*)(lds + 8192 + row * 64 + ((g ^ (row & 3)) * 16));
        }
#pragma unroll
        for (int mf = 0; mf < 4; ++mf)
#pragma unroll
            for (int nf = 0; nf < 4; ++nf)
                acc[mf][nf] = __builtin_amdgcn_mfma_f32_16x16x32_bf16(aF[mf], bF[nf], acc[mf][nf], 0, 0, 0);
    }

#pragma unroll
    for (int nf = 0; nf < 4; ++nf) {
        int n = n0 + wc * 64 + nf * 16 + c;
        float bv = bias[n];
#pragma unroll
        for (int mf = 0; mf < 4; ++mf)
#pragma unroll
            for (int r = 0; r < 4; ++r) {
                int mrow = m0 + wr * 64 + mf * 16 + g * 4 + r;
                out[(size_t)mrow * C_ + n] = acc[mf][nf][r] + bv;
            }
    }
}

} // namespace

extern "C" void kernel_launch(void* const* d_in, const int* in_sizes, int n_in,
                              void* d_out, int out_size, void* d_ws, size_t ws_size,
                              hipStream_t stream) {
    const float* x     = (const float*)d_in[0];
    const float* w_qkv = (const float*)d_in[1];
    const float* w_out = (const float*)d_in[2];
    const float* b_out = (const float*)d_in[3];
    float* out = (float*)d_out;

    char* ws = (char*)d_ws;
    float2* cs = (float2*)ws;                               // 512KB
    u16* xb   = (u16*)(ws + 524288);                        // 8MB
    u16* wqb  = (u16*)(ws + 524288 + 8388608);              // 6MB
    u16* wob  = (u16*)(ws + 524288 + 8388608 + 6291456);    // 2MB
    u16* qb   = (u16*)(ws + 17301504);                      // 8MB
    u16* kb   = (u16*)(ws + 25690112);                      // 8MB
    u16* vt   = (u16*)(ws + 34078720);                      // 8MB
    u16* attb = (u16*)(ws + 42467328);                      // 8MB

    tab_k<<<256, 256, 0, stream>>>(cs);
    cvt_k<<<8192, 256, 0, stream>>>((const float4*)x, (const float4*)w_qkv,
                                    (const float4*)w_out, (uint2*)xb, (uint2*)wqb, (uint2*)wob);
    qkv_mfma_k<<<dim3(24, 32), 256, 0, stream>>>(xb, wqb, cs, qb, kb, vt);
    flash_mfma_k<<<dim3(32, 16), 256, 0, stream>>>(qb, kb, vt, attb);
    proj_mfma_k<<<dim3(8, 32), 256, 0, stream>>>(attb, wob, b_out, out);
}

// Round 4
// 227.646 us; speedup vs baseline: 4.9804x; 1.1320x over previous
//
#include <hip/hip_runtime.h>
#include <math.h>

namespace {

typedef __attribute__((ext_vector_type(8))) short s16x8;
typedef __attribute__((ext_vector_type(4))) float f32x4;
typedef unsigned int u32;
typedef unsigned short u16;

constexpr int B_ = 2;
constexpr int T_ = 2048;
constexpr int C_ = 1024;
constexpr int H_ = 16;
constexpr float L2E = 1.44269504088896340736f;

__device__ inline u16 f2bf(float x) {
    __bf16 h = (__bf16)x;
    return __builtin_bit_cast(u16, h);
}
__device__ inline u32 packbf2(float a, float b) {
    return (u32)f2bf(a) | ((u32)f2bf(b) << 16);
}
__device__ inline void gload_lds16(const void* g, void* lds) {
    __builtin_amdgcn_global_load_lds(
        (const __attribute__((address_space(1))) unsigned int*)g,
        (__attribute__((address_space(3))) unsigned int*)lds, 16, 0, 0);
}

// ---------------------------------------------------------------- RoPE table
__global__ __launch_bounds__(256) void tab_k(float2* __restrict__ cs) {
    int idx = blockIdx.x * 256 + threadIdx.x;   // 65536
    int t = idx >> 5, i = idx & 31;
    float inv = 1.0f / powf(10000.0f, (float)i / 32.0f);
    float ang = (float)t * inv;
    cs[idx] = make_float2(cosf(ang), sinf(ang));
}

// ---------------------------------------------------------------- f32 -> bf16 convert
__global__ __launch_bounds__(256)
void cvt_k(const float4* __restrict__ x, const float4* __restrict__ wq,
           const float4* __restrict__ wo, uint2* __restrict__ xb,
           uint2* __restrict__ wqb, uint2* __restrict__ wob) {
    int i = blockIdx.x * 256 + threadIdx.x;   // 2097152 total
    const float4* s;
    uint2* d;
    int j;
    if (i < 1048576) { s = x; d = xb; j = i; }
    else if (i < 1048576 + 786432) { s = wq; d = wqb; j = i - 1048576; }
    else { s = wo; d = wob; j = i - (1048576 + 786432); }
    float4 v = s[j];
    d[j] = make_uint2(packbf2(v.x, v.y), packbf2(v.z, v.w));
}

// ---------------------------------------------------------------- QKV MFMA GEMM + RoPE
__global__ __launch_bounds__(256)
void qkv_mfma_k(const u16* __restrict__ xb, const u16* __restrict__ wqb,
                const float2* __restrict__ cs, u16* __restrict__ qb,
                u16* __restrict__ kb, u16* __restrict__ vt) {
    __shared__ char lds[16384];       // A 8KB | B 8KB, rows 64B, swizzle ^((row&3)<<4)
    const int tid = threadIdx.x;
    const int w = tid >> 6, lane = tid & 63;
    const int c = lane & 15, g = lane >> 4;
    const int n0 = blockIdx.x * 128, m0 = blockIdx.y * 128;
    const int wr = w >> 1, wc = w & 1;

    f32x4 acc[4][4];
#pragma unroll
    for (int i = 0; i < 4; ++i)
#pragma unroll
        for (int j = 0; j < 4; ++j) acc[i][j] = (f32x4){0.f, 0.f, 0.f, 0.f};

    const u16* Ab = xb + (size_t)m0 * C_;
    const u16* Bb = wqb + (size_t)n0 * C_;
    const int srow = tid >> 2, sslot = tid & 3;

    for (int k0 = 0; k0 < C_; k0 += 32) {
        __syncthreads();
#pragma unroll
        for (int call = 0; call < 2; ++call) {
            int r = call * 64 + srow;
            int ds = sslot ^ (r & 3);
            gload_lds16(Ab + (size_t)r * C_ + k0 + ds * 8, lds + call * 4096 + w * 1024);
            gload_lds16(Bb + (size_t)r * C_ + k0 + ds * 8, lds + 8192 + call * 4096 + w * 1024);
        }
        __syncthreads();
        s16x8 aF[4], bF[4];
#pragma unroll
        for (int mf = 0; mf < 4; ++mf) {
            int row = wr * 64 + mf * 16 + c;
            aF[mf] = *(const s16x8*)(lds + row * 64 + ((g ^ (row & 3)) * 16));
        }
#pragma unroll
        for (int nf = 0; nf < 4; ++nf) {
            int row = wc * 64 + nf * 16 + c;
            bF[nf] = *(const s16x8*)(lds + 8192 + row * 64 + ((g ^ (row & 3)) * 16));
        }
#pragma unroll
        for (int mf = 0; mf < 4; ++mf)
#pragma unroll
            for (int nf = 0; nf < 4; ++nf)
                acc[mf][nf] = __builtin_amdgcn_mfma_f32_16x16x32_bf16(aF[mf], bF[nf], acc[mf][nf], 0, 0, 0);
    }

    // epilogue
    const int sec = n0 >> 10;
    const int h = ((n0 & 1023) >> 6) + wc;
    const int b = m0 >> 11;
    const int t0w = (m0 & 2047) + wr * 64;
    const int bh = b * H_ + h;
    if (sec < 2) {
        u16* dst = (sec == 0) ? qb : kb;
        const float qs = (sec == 0) ? 0.125f : 1.0f;
#pragma unroll
        for (int nf = 0; nf < 4; ++nf) {
            int d = nf * 16 + c;
            int ibase = nf * 8 + (c >> 1);
#pragma unroll
            for (int mf = 0; mf < 4; ++mf) {
#pragma unroll
                for (int r = 0; r < 4; ++r) {
                    int t = t0w + mf * 16 + g * 4 + r;
                    float own = acc[mf][nf][r];
                    float partner = __shfl_xor(own, 1);
                    float2 csv = cs[t * 32 + ibase];
                    float rot = (d & 1) ? (own * csv.x + partner * csv.y)
                                        : (own * csv.x - partner * csv.y);
                    rot *= qs;
                    float rothi = __shfl_xor(rot, 1);
                    if (!(d & 1))
                        *(u32*)(dst + ((size_t)bh * T_ + t) * 64 + d) = packbf2(rot, rothi);
                }
            }
        }
    } else {
#pragma unroll
        for (int nf = 0; nf < 4; ++nf) {
            int d = nf * 16 + c;
#pragma unroll
            for (int mf = 0; mf < 4; ++mf) {
                int tb = t0w + mf * 16 + g * 4;
                u32 lo = packbf2(acc[mf][nf][0], acc[mf][nf][1]);
                u32 hi = packbf2(acc[mf][nf][2], acc[mf][nf][3]);
                *(uint2*)(vt + ((size_t)bh * 64 + d) * T_ + tb) = make_uint2(lo, hi);
            }
        }
    }
}

// ---------------------------------------------------------------- flash attention (bf16 MFMA)
// 64 q-rows per block, 4 waves x 16 rows; KV tiles of 64; descending-work
// dispatch (qi = 31 - blockIdx.y) for load balance; 32KB LDS -> 5 blocks/CU.
__global__ __launch_bounds__(256)
void flash_mfma_k(const u16* __restrict__ qb, const u16* __restrict__ kb,
                  const u16* __restrict__ vt, u16* __restrict__ attb) {
    __shared__ char lds[32768];
    char* Qs = lds;                // 8KB: 64 rows x 128B, swz ^((row&7)<<4)
    char* Ks = lds + 8192;         // 8KB
    char* Vs = lds + 16384;        // 8KB: V^T tile (rows = d)
    char* Ps = lds + 24576;        // 8KB: per-wave 2KB, 16 rows x 128B
    const int tid = threadIdx.x, w = tid >> 6, lane = tid & 63;
    const int c = lane & 15, g = lane >> 4;
    const int bh = blockIdx.x;
    const int qi = 31 - blockIdx.y;          // heavy tiles dispatch first
    const int q0 = qi * 64, q0w = q0 + w * 16;
    const u16* Qg = qb + ((size_t)bh * T_ + q0) * 64;
    const u16* Kg = kb + (size_t)bh * T_ * 64;
    const u16* Vg = vt + (size_t)bh * 64 * T_;

    // stage Q (8KB, swizzled source)
#pragma unroll
    for (int call = 0; call < 2; ++call) {
        int row = call * 32 + (tid >> 3);
        int ds = (tid & 7) ^ (row & 7);
        gload_lds16(Qg + (size_t)row * 64 + ds * 8, Qs + call * 4096 + w * 1024);
    }
    __syncthreads();

    s16x8 bQ[2];
#pragma unroll
    for (int kc = 0; kc < 2; ++kc) {
        int row = w * 16 + c;
        bQ[kc] = *(const s16x8*)(Qs + row * 128 + (((kc * 4 + g) ^ (row & 7)) * 16));
    }

    float m_ = -INFINITY, l_ = 0.f;
    f32x4 accO[4];
#pragma unroll
    for (int j = 0; j < 4; ++j) accO[j] = (f32x4){0.f, 0.f, 0.f, 0.f};

    const int nt = qi + 1;
    for (int kt = 0; kt < nt; ++kt) {
        __syncthreads();
        {
            int row = tid >> 3, slot = tid & 7;
#pragma unroll
            for (int call = 0; call < 2; ++call) {
                int r = call * 32 + row;
                int ds = slot ^ (r & 7);
                gload_lds16(Kg + (size_t)(kt * 64 + r) * 64 + ds * 8, Ks + call * 4096 + w * 1024);
                gload_lds16(Vg + (size_t)r * T_ + kt * 64 + ds * 8, Vs + call * 4096 + w * 1024);
            }
        }
        __syncthreads();

        // S^T = K . Q^T   (row=kv=(g*4+r)+16mf, col=qrow=c)
        f32x4 S[4];
#pragma unroll
        for (int mf = 0; mf < 4; ++mf) S[mf] = (f32x4){0.f, 0.f, 0.f, 0.f};
        s16x8 aK[4][2];
#pragma unroll
        for (int mf = 0; mf < 4; ++mf)
#pragma unroll
            for (int kc = 0; kc < 2; ++kc) {
                int row = mf * 16 + c;
                aK[mf][kc] = *(const s16x8*)(Ks + row * 128 + (((kc * 4 + g) ^ (row & 7)) * 16));
            }
#pragma unroll
        for (int kc = 0; kc < 2; ++kc)
#pragma unroll
            for (int mf = 0; mf < 4; ++mf)
                S[mf] = __builtin_amdgcn_mfma_f32_16x16x32_bf16(aK[mf][kc], bQ[kc], S[mf], 0, 0, 0);

        // causal mask (only the diagonal tile needs it)
        if (kt == qi) {
#pragma unroll
            for (int mf = 0; mf < 4; ++mf)
#pragma unroll
                for (int r = 0; r < 4; ++r) {
                    int kvg = kt * 64 + mf * 16 + g * 4 + r;
                    if (kvg > q0w + c) S[mf][r] = -INFINITY;
                }
        }

        // online softmax (q pre-scaled by 0.125); defer-max (skip rescale)
        float mx = -INFINITY;
#pragma unroll
        for (int mf = 0; mf < 4; ++mf)
#pragma unroll
            for (int r = 0; r < 4; ++r) mx = fmaxf(mx, S[mf][r]);
        mx = fmaxf(mx, __shfl_xor(mx, 16));
        mx = fmaxf(mx, __shfl_xor(mx, 32));
        float alpha = 1.0f;
        if (!__all(mx - m_ <= 8.0f)) {
            float mnew = fmaxf(m_, mx);
            alpha = exp2f((m_ - mnew) * L2E);
            m_ = mnew;
#pragma unroll
            for (int r = 0; r < 4; ++r) {
                float ar = __shfl(alpha, g * 4 + r);
#pragma unroll
                for (int nd = 0; nd < 4; ++nd) accO[nd][r] *= ar;
            }
        }
        float sum = 0.f;
#pragma unroll
        for (int mf = 0; mf < 4; ++mf)
#pragma unroll
            for (int r = 0; r < 4; ++r) {
                float p = exp2f((S[mf][r] - m_) * L2E);
                S[mf][r] = p;
                sum += p;
            }
        sum += __shfl_xor(sum, 16);
        sum += __shfl_xor(sum, 32);
        l_ = l_ * alpha + sum;

        // P -> LDS (P[qrow=c][kv], swizzled)
#pragma unroll
        for (int mf = 0; mf < 4; ++mf)
#pragma unroll
            for (int p2 = 0; p2 < 2; ++p2) {
                u32 v = packbf2(S[mf][2 * p2], S[mf][2 * p2 + 1]);
                int off = (mf * 16 + g * 4 + p2 * 2) * 2;
                *(u32*)(Ps + w * 2048 + c * 128 + (off ^ ((c & 7) << 4))) = v;
            }
        // order u32 P-stores before s16x8 P-loads (TBAA hoist hazard)
        __threadfence_block();

        // PV: O += P . V
        s16x8 aP[2], bV[4][2];
#pragma unroll
        for (int kc = 0; kc < 2; ++kc)
            aP[kc] = *(const s16x8*)(Ps + w * 2048 + c * 128 + (((kc * 4 + g) ^ (c & 7)) * 16));
#pragma unroll
        for (int nd = 0; nd < 4; ++nd)
#pragma unroll
            for (int kc = 0; kc < 2; ++kc) {
                int row = nd * 16 + c;
                bV[nd][kc] = *(const s16x8*)(Vs + row * 128 + (((kc * 4 + g) ^ (row & 7)) * 16));
            }
#pragma unroll
        for (int kc = 0; kc < 2; ++kc)
#pragma unroll
            for (int nd = 0; nd < 4; ++nd)
                accO[nd] = __builtin_amdgcn_mfma_f32_16x16x32_bf16(aP[kc], bV[nd][kc], accO[nd], 0, 0, 0);
    }

    // epilogue: attb[b*T + t][h*64 + d]
    const int hh = bh & 15;
    const int bb = bh >> 4;
#pragma unroll
    for (int r = 0; r < 4; ++r) {
        float linv = 1.0f / __shfl(l_, g * 4 + r);
        int t = q0w + g * 4 + r;
        size_t rowb = ((size_t)bb * T_ + t) * C_ + hh * 64;
#pragma unroll
        for (int nd = 0; nd < 4; ++nd)
            attb[rowb + nd * 16 + c] = f2bf(accO[nd][r] * linv);
    }
}

// ---------------------------------------------------------------- out-proj MFMA GEMM + bias
__global__ __launch_bounds__(256)
void proj_mfma_k(const u16* __restrict__ attb, const u16* __restrict__ wob,
                 const float* __restrict__ bias, float* __restrict__ out) {
    __shared__ char lds[16384];
    const int tid = threadIdx.x;
    const int w = tid >> 6, lane = tid & 63;
    const int c = lane & 15, g = lane >> 4;
    const int n0 = blockIdx.x * 128, m0 = blockIdx.y * 128;
    const int wr = w >> 1, wc = w & 1;

    f32x4 acc[4][4];
#pragma unroll
    for (int i = 0; i < 4; ++i)
#pragma unroll
        for (int j = 0; j < 4; ++j) acc[i][j] = (f32x4){0.f, 0.f, 0.f, 0.f};

    const u16* Ab = attb + (size_t)m0 * C_;
    const u16* Bb = wob + (size_t)n0 * C_;
    const int srow = tid >> 2, sslot = tid & 3;

    for (int k0 = 0; k0 < C_; k0 += 32) {
        __syncthreads();
#pragma unroll
        for (int call = 0; call < 2; ++call) {
            int r = call * 64 + srow;
            int ds = sslot ^ (r & 3);
            gload_lds16(Ab + (size_t)r * C_ + k0 + ds * 8, lds + call * 4096 + w * 1024);
            gload_lds16(Bb + (size_t)r * C_ + k0 + ds * 8, lds + 8192 + call * 4096 + w * 1024);
        }
        __syncthreads();
        s16x8 aF[4], bF[4];
#pragma unroll
        for (int mf = 0; mf < 4; ++mf) {
            int row = wr * 64 + mf * 16 + c;
            aF[mf] = *(const s16x8*)(lds + row * 64 + ((g ^ (row & 3)) * 16));
        }
#pragma unroll
        for (int nf = 0; nf < 4; ++nf) {
            int row = wc * 64 + nf * 16 + c;
            bF[nf] = *(const s16x8*)(lds + 8192 + row * 64 + ((g ^ (row & 3)) * 16));
        }
#pragma unroll
        for (int mf = 0; mf < 4; ++mf)
#pragma unroll
            for (int nf = 0; nf < 4; ++nf)
                acc[mf][nf] = __builtin_amdgcn_mfma_f32_16x16x32_bf16(aF[mf], bF[nf], acc[mf][nf], 0, 0, 0);
    }

#pragma unroll
    for (int nf = 0; nf < 4; ++nf) {
        int n = n0 + wc * 64 + nf * 16 + c;
        float bv = bias[n];
#pragma unroll
        for (int mf = 0; mf < 4; ++mf)
#pragma unroll
            for (int r = 0; r < 4; ++r) {
                int mrow = m0 + wr * 64 + mf * 16 + g * 4 + r;
                out[(size_t)mrow * C_ + n] = acc[mf][nf][r] + bv;
            }
    }
}

} // namespace

extern "C" void kernel_launch(void* const* d_in, const int* in_sizes, int n_in,
                              void* d_out, int out_size, void* d_ws, size_t ws_size,
                              hipStream_t stream) {
    const float* x     = (const float*)d_in[0];
    const float* w_qkv = (const float*)d_in[1];
    const float* w_out = (const float*)d_in[2];
    const float* b_out = (const float*)d_in[3];
    float* out = (float*)d_out;

    char* ws = (char*)d_ws;
    float2* cs = (float2*)ws;                               // 512KB
    u16* xb   = (u16*)(ws + 524288);                        // 8MB
    u16* wqb  = (u16*)(ws + 524288 + 8388608);              // 6MB
    u16* wob  = (u16*)(ws + 524288 + 8388608 + 6291456);    // 2MB
    u16* qb   = (u16*)(ws + 17301504);                      // 8MB
    u16* kb   = (u16*)(ws + 25690112);                      // 8MB
    u16* vt   = (u16*)(ws + 34078720);                      // 8MB
    u16* attb = (u16*)(ws + 42467328);                      // 8MB

    tab_k<<<256, 256, 0, stream>>>(cs);
    cvt_k<<<8192, 256, 0, stream>>>((const float4*)x, (const float4*)w_qkv,
                                    (const float4*)w_out, (uint2*)xb, (uint2*)wqb, (uint2*)wob);
    qkv_mfma_k<<<dim3(24, 32), 256, 0, stream>>>(xb, wqb, cs, qb, kb, vt);
    flash_mfma_k<<<dim3(32, 32), 256, 0, stream>>>(qb, kb, vt, attb);
    proj_mfma_k<<<dim3(8, 32), 256, 0, stream>>>(attb, wob, b_out, out);
}

// Round 6
// 223.983 us; speedup vs baseline: 5.0618x; 1.0164x over previous
//
#include <hip/hip_runtime.h>
#include <math.h>

namespace {

typedef __attribute__((ext_vector_type(8))) short s16x8;
typedef __attribute__((ext_vector_type(4))) float f32x4;
typedef unsigned int u32;
typedef unsigned short u16;

constexpr int B_ = 2;
constexpr int T_ = 2048;
constexpr int C_ = 1024;
constexpr int H_ = 16;
constexpr float L2E = 1.44269504088896340736f;

__device__ inline u16 f2bf(float x) {
    __bf16 h = (__bf16)x;
    return __builtin_bit_cast(u16, h);
}
__device__ inline u32 packbf2(float a, float b) {
    return (u32)f2bf(a) | ((u32)f2bf(b) << 16);
}
__device__ inline void gload_lds16(const void* g, void* lds) {
    __builtin_amdgcn_global_load_lds(
        (const __attribute__((address_space(1))) unsigned int*)g,
        (__attribute__((address_space(3))) unsigned int*)lds, 16, 0, 0);
}

// ---------------------------------------------------------------- RoPE table
__global__ __launch_bounds__(256) void tab_k(float2* __restrict__ cs) {
    int idx = blockIdx.x * 256 + threadIdx.x;   // 65536
    int t = idx >> 5, i = idx & 31;
    float inv = 1.0f / powf(10000.0f, (float)i / 32.0f);
    float ang = (float)t * inv;
    cs[idx] = make_float2(cosf(ang), sinf(ang));
}

// ---------------------------------------------------------------- f32 -> bf16 convert
__global__ __launch_bounds__(256)
void cvt_k(const float4* __restrict__ x, const float4* __restrict__ wq,
           const float4* __restrict__ wo, uint2* __restrict__ xb,
           uint2* __restrict__ wqb, uint2* __restrict__ wob) {
    int i = blockIdx.x * 256 + threadIdx.x;   // 2097152 total
    const float4* s;
    uint2* d;
    int j;
    if (i < 1048576) { s = x; d = xb; j = i; }
    else if (i < 1048576 + 786432) { s = wq; d = wqb; j = i - 1048576; }
    else { s = wo; d = wob; j = i - (1048576 + 786432); }
    float4 v = s[j];
    d[j] = make_uint2(packbf2(v.x, v.y), packbf2(v.z, v.w));
}

// ---------------------------------------------------------------- QKV MFMA GEMM + RoPE
// 128x128 tile, BK=32, 2-phase double-buffered LDS (T3 minimum recipe):
// prologue-stage tile0; per step: STAGE(t+1 -> buf^1) || compute(buf); 1 barrier.
// Swizzle key (r>>1)&3 -> fragment ds_read_b128 is 2-way (free) instead of 4-way.
__global__ __launch_bounds__(256)
void qkv_mfma_k(const u16* __restrict__ xb, const u16* __restrict__ wqb,
                const float2* __restrict__ cs, u16* __restrict__ qb,
                u16* __restrict__ kb, u16* __restrict__ vt) {
    __shared__ char lds[32768];       // buf0: A 8K | B 8K ; buf1: A 8K | B 8K
    const int tid = threadIdx.x;
    const int w = tid >> 6, lane = tid & 63;
    const int c = lane & 15, g = lane >> 4;
    const int n0 = blockIdx.x * 128, m0 = blockIdx.y * 128;
    const int wr = w >> 1, wc = w & 1;

    f32x4 acc[4][4];
#pragma unroll
    for (int i = 0; i < 4; ++i)
#pragma unroll
        for (int j = 0; j < 4; ++j) acc[i][j] = (f32x4){0.f, 0.f, 0.f, 0.f};

    const u16* Ab = xb + (size_t)m0 * C_;
    const u16* Bb = wqb + (size_t)n0 * C_;
    const int srow = tid >> 2, sslot = tid & 3;

    auto stage = [&](int k0, char* base) {
#pragma unroll
        for (int call = 0; call < 2; ++call) {
            int r = call * 64 + srow;
            int ds = sslot ^ ((r >> 1) & 3);
            gload_lds16(Ab + (size_t)r * C_ + k0 + ds * 8, base + call * 4096 + w * 1024);
            gload_lds16(Bb + (size_t)r * C_ + k0 + ds * 8, base + 8192 + call * 4096 + w * 1024);
        }
    };
    auto compute = [&](const char* base) {
        s16x8 aF[4], bF[4];
#pragma unroll
        for (int mf = 0; mf < 4; ++mf) {
            int row = wr * 64 + mf * 16 + c;
            aF[mf] = *(const s16x8*)(base + row * 64 + ((g ^ ((row >> 1) & 3)) * 16));
        }
#pragma unroll
        for (int nf = 0; nf < 4; ++nf) {
            int row = wc * 64 + nf * 16 + c;
            bF[nf] = *(const s16x8*)(base + 8192 + row * 64 + ((g ^ ((row >> 1) & 3)) * 16));
        }
#pragma unroll
        for (int mf = 0; mf < 4; ++mf)
#pragma unroll
            for (int nf = 0; nf < 4; ++nf)
                acc[mf][nf] = __builtin_amdgcn_mfma_f32_16x16x32_bf16(aF[mf], bF[nf], acc[mf][nf], 0, 0, 0);
    };

    stage(0, lds);
    __syncthreads();
    int cur = 0;
    for (int t = 0; t < 31; ++t) {
        stage((t + 1) * 32, lds + ((cur ^ 1) << 14));
        compute(lds + (cur << 14));
        __syncthreads();          // vmcnt(0)+lgkmcnt(0)+barrier: next buf ready
        cur ^= 1;
    }
    compute(lds + (cur << 14));

    // epilogue
    const int sec = n0 >> 10;
    const int h = ((n0 & 1023) >> 6) + wc;
    const int b = m0 >> 11;
    const int t0w = (m0 & 2047) + wr * 64;
    const int bh = b * H_ + h;
    if (sec < 2) {
        u16* dst = (sec == 0) ? qb : kb;
        const float qs = (sec == 0) ? 0.125f : 1.0f;
#pragma unroll
        for (int nf = 0; nf < 4; ++nf) {
            int d = nf * 16 + c;
            int ibase = nf * 8 + (c >> 1);
#pragma unroll
            for (int mf = 0; mf < 4; ++mf) {
#pragma unroll
                for (int r = 0; r < 4; ++r) {
                    int t = t0w + mf * 16 + g * 4 + r;
                    float own = acc[mf][nf][r];
                    float partner = __shfl_xor(own, 1);
                    float2 csv = cs[t * 32 + ibase];
                    float rot = (d & 1) ? (own * csv.x + partner * csv.y)
                                        : (own * csv.x - partner * csv.y);
                    rot *= qs;
                    float rothi = __shfl_xor(rot, 1);
                    if (!(d & 1))
                        *(u32*)(dst + ((size_t)bh * T_ + t) * 64 + d) = packbf2(rot, rothi);
                }
            }
        }
    } else {
#pragma unroll
        for (int nf = 0; nf < 4; ++nf) {
            int d = nf * 16 + c;
#pragma unroll
            for (int mf = 0; mf < 4; ++mf) {
                int tb = t0w + mf * 16 + g * 4;
                u32 lo = packbf2(acc[mf][nf][0], acc[mf][nf][1]);
                u32 hi = packbf2(acc[mf][nf][2], acc[mf][nf][3]);
                *(uint2*)(vt + ((size_t)bh * 64 + d) * T_ + tb) = make_uint2(lo, hi);
            }
        }
    }
}

// ---------------------------------------------------------------- flash attention (bf16 MFMA)
// 64 q-rows per block, 4 waves x 16 rows; KV tiles of 64; descending-work
// dispatch (qi = 31 - blockIdx.y) for load balance; 32KB LDS -> 5 blocks/CU.
__global__ __launch_bounds__(256)
void flash_mfma_k(const u16* __restrict__ qb, const u16* __restrict__ kb,
                  const u16* __restrict__ vt, u16* __restrict__ attb) {
    __shared__ char lds[32768];
    char* Qs = lds;                // 8KB: 64 rows x 128B, swz ^((row&7)<<4)
    char* Ks = lds + 8192;         // 8KB
    char* Vs = lds + 16384;        // 8KB: V^T tile (rows = d)
    char* Ps = lds + 24576;        // 8KB: per-wave 2KB, 16 rows x 128B
    const int tid = threadIdx.x, w = tid >> 6, lane = tid & 63;
    const int c = lane & 15, g = lane >> 4;
    const int bh = blockIdx.x;
    const int qi = 31 - blockIdx.y;          // heavy tiles dispatch first
    const int q0 = qi * 64, q0w = q0 + w * 16;
    const u16* Qg = qb + ((size_t)bh * T_ + q0) * 64;
    const u16* Kg = kb + (size_t)bh * T_ * 64;
    const u16* Vg = vt + (size_t)bh * 64 * T_;

    // stage Q (8KB, swizzled source)
#pragma unroll
    for (int call = 0; call < 2; ++call) {
        int row = call * 32 + (tid >> 3);
        int ds = (tid & 7) ^ (row & 7);
        gload_lds16(Qg + (size_t)row * 64 + ds * 8, Qs + call * 4096 + w * 1024);
    }
    __syncthreads();

    s16x8 bQ[2];
#pragma unroll
    for (int kc = 0; kc < 2; ++kc) {
        int row = w * 16 + c;
        bQ[kc] = *(const s16x8*)(Qs + row * 128 + (((kc * 4 + g) ^ (row & 7)) * 16));
    }

    float m_ = -INFINITY, l_ = 0.f;
    f32x4 accO[4];
#pragma unroll
    for (int j = 0; j < 4; ++j) accO[j] = (f32x4){0.f, 0.f, 0.f, 0.f};

    const int nt = qi + 1;
    for (int kt = 0; kt < nt; ++kt) {
        __syncthreads();
        {
            int row = tid >> 3, slot = tid & 7;
#pragma unroll
            for (int call = 0; call < 2; ++call) {
                int r = call * 32 + row;
                int ds = slot ^ (r & 7);
                gload_lds16(Kg + (size_t)(kt * 64 + r) * 64 + ds * 8, Ks + call * 4096 + w * 1024);
                gload_lds16(Vg + (size_t)r * T_ + kt * 64 + ds * 8, Vs + call * 4096 + w * 1024);
            }
        }
        __syncthreads();

        // S^T = K . Q^T   (row=kv=(g*4+r)+16mf, col=qrow=c)
        f32x4 S[4];
#pragma unroll
        for (int mf = 0; mf < 4; ++mf) S[mf] = (f32x4){0.f, 0.f, 0.f, 0.f};
        s16x8 aK[4][2];
#pragma unroll
        for (int mf = 0; mf < 4; ++mf)
#pragma unroll
            for (int kc = 0; kc < 2; ++kc) {
                int row = mf * 16 + c;
                aK[mf][kc] = *(const s16x8*)(Ks + row * 128 + (((kc * 4 + g) ^ (row & 7)) * 16));
            }
#pragma unroll
        for (int kc = 0; kc < 2; ++kc)
#pragma unroll
            for (int mf = 0; mf < 4; ++mf)
                S[mf] = __builtin_amdgcn_mfma_f32_16x16x32_bf16(aK[mf][kc], bQ[kc], S[mf], 0, 0, 0);

        // causal mask (only the diagonal tile needs it)
        if (kt == qi) {
#pragma unroll
            for (int mf = 0; mf < 4; ++mf)
#pragma unroll
                for (int r = 0; r < 4; ++r) {
                    int kvg = kt * 64 + mf * 16 + g * 4 + r;
                    if (kvg > q0w + c) S[mf][r] = -INFINITY;
                }
        }

        // online softmax (q pre-scaled by 0.125); defer-max (skip rescale)
        float mx = -INFINITY;
#pragma unroll
        for (int mf = 0; mf < 4; ++mf)
#pragma unroll
            for (int r = 0; r < 4; ++r) mx = fmaxf(mx, S[mf][r]);
        mx = fmaxf(mx, __shfl_xor(mx, 16));
        mx = fmaxf(mx, __shfl_xor(mx, 32));
        float alpha = 1.0f;
        if (!__all(mx - m_ <= 8.0f)) {
            float mnew = fmaxf(m_, mx);
            alpha = exp2f((m_ - mnew) * L2E);
            m_ = mnew;
#pragma unroll
            for (int r = 0; r < 4; ++r) {
                float ar = __shfl(alpha, g * 4 + r);
#pragma unroll
                for (int nd = 0; nd < 4; ++nd) accO[nd][r] *= ar;
            }
        }
        float sum = 0.f;
#pragma unroll
        for (int mf = 0; mf < 4; ++mf)
#pragma unroll
            for (int r = 0; r < 4; ++r) {
                float p = exp2f((S[mf][r] - m_) * L2E);
                S[mf][r] = p;
                sum += p;
            }
        sum += __shfl_xor(sum, 16);
        sum += __shfl_xor(sum, 32);
        l_ = l_ * alpha + sum;

        // P -> LDS (P[qrow=c][kv], swizzled)
#pragma unroll
        for (int mf = 0; mf < 4; ++mf)
#pragma unroll
            for (int p2 = 0; p2 < 2; ++p2) {
                u32 v = packbf2(S[mf][2 * p2], S[mf][2 * p2 + 1]);
                int off = (mf * 16 + g * 4 + p2 * 2) * 2;
                *(u32*)(Ps + w * 2048 + c * 128 + (off ^ ((c & 7) << 4))) = v;
            }
        // order u32 P-stores before s16x8 P-loads (TBAA hoist hazard)
        __threadfence_block();

        // PV: O += P . V
        s16x8 aP[2], bV[4][2];
#pragma unroll
        for (int kc = 0; kc < 2; ++kc)
            aP[kc] = *(const s16x8*)(Ps + w * 2048 + c * 128 + (((kc * 4 + g) ^ (c & 7)) * 16));
#pragma unroll
        for (int nd = 0; nd < 4; ++nd)
#pragma unroll
            for (int kc = 0; kc < 2; ++kc) {
                int row = nd * 16 + c;
                bV[nd][kc] = *(const s16x8*)(Vs + row * 128 + (((kc * 4 + g) ^ (row & 7)) * 16));
            }
#pragma unroll
        for (int kc = 0; kc < 2; ++kc)
#pragma unroll
            for (int nd = 0; nd < 4; ++nd)
                accO[nd] = __builtin_amdgcn_mfma_f32_16x16x32_bf16(aP[kc], bV[nd][kc], accO[nd], 0, 0, 0);
    }

    // epilogue: attb[b*T + t][h*64 + d]
    const int hh = bh & 15;
    const int bb = bh >> 4;
#pragma unroll
    for (int r = 0; r < 4; ++r) {
        float linv = 1.0f / __shfl(l_, g * 4 + r);
        int t = q0w + g * 4 + r;
        size_t rowb = ((size_t)bb * T_ + t) * C_ + hh * 64;
#pragma unroll
        for (int nd = 0; nd < 4; ++nd)
            attb[rowb + nd * 16 + c] = f2bf(accO[nd][r] * linv);
    }
}

// ---------------------------------------------------------------- out-proj MFMA GEMM + bias
// same 2-phase double-buffered structure as qkv_mfma_k
__global__ __launch_bounds__(256)
void proj_mfma_k(const u16* __restrict__ attb, const u16* __restrict__ wob,
                 const float* __restrict__ bias, float* __restrict__ out) {
    __shared__ char lds[32768];
    const int tid = threadIdx.x;
    const int w = tid >> 6, lane = tid & 63;
    const int c = lane & 15, g = lane >> 4;
    const int n0 = blockIdx.x * 128, m0 = blockIdx.y * 128;
    const int wr = w >> 1, wc = w & 1;

    f32x4 acc[4][4];
#pragma unroll
    for (int i = 0; i < 4; ++i)
#pragma unroll
        for (int j = 0; j < 4; ++j) acc[i][j] = (f32x4){0.f, 0.f, 0.f, 0.f};

    const u16* Ab = attb + (size_t)m0 * C_;
    const u16* Bb = wob + (size_t)n0 * C_;
    const int srow = tid >> 2, sslot = tid & 3;

    auto stage = [&](int k0, char* base) {
#pragma unroll
        for (int call = 0; call < 2; ++call) {
            int r = call * 64 + srow;
            int ds = sslot ^ ((r >> 1) & 3);
            gload_lds16(Ab + (size_t)r * C_ + k0 + ds * 8, base + call * 4096 + w * 1024);
            gload_lds16(Bb + (size_t)r * C_ + k0 + ds * 8, base + 8192 + call * 4096 + w * 1024);
        }
    };
    auto compute = [&](const char* base) {
        s16x8 aF[4], bF[4];
#pragma unroll
        for (int mf = 0; mf < 4; ++mf) {
            int row = wr * 64 + mf * 16 + c;
            aF[mf] = *(const s16x8*)(base + row * 64 + ((g ^ ((row >> 1) & 3)) * 16));
        }
#pragma unroll
        for (int nf = 0; nf < 4; ++nf) {
            int row = wc * 64 + nf * 16 + c;
            bF[nf] = *(const s16x8*)(base + 8192 + row * 64 + ((g ^ ((row >> 1) & 3)) * 16));
        }
#pragma unroll
        for (int mf = 0; mf < 4; ++mf)
#pragma unroll
            for (int nf = 0; nf < 4; ++nf)
                acc[mf][nf] = __builtin_amdgcn_mfma_f32_16x16x32_bf16(aF[mf], bF[nf], acc[mf][nf], 0, 0, 0);
    };

    stage(0, lds);
    __syncthreads();
    int cur = 0;
    for (int t = 0; t < 31; ++t) {
        stage((t + 1) * 32, lds + ((cur ^ 1) << 14));
        compute(lds + (cur << 14));
        __syncthreads();
        cur ^= 1;
    }
    compute(lds + (cur << 14));

#pragma unroll
    for (int nf = 0; nf < 4; ++nf) {
        int n = n0 + wc * 64 + nf * 16 + c;
        float bv = bias[n];
#pragma unroll
        for (int mf = 0; mf < 4; ++mf)
#pragma unroll
            for (int r = 0; r < 4; ++r) {
                int mrow = m0 + wr * 64 + mf * 16 + g * 4 + r;
                out[(size_t)mrow * C_ + n] = acc[mf][nf][r] + bv;
            }
    }
}

} // namespace

extern "C" void kernel_launch(void* const* d_in, const int* in_sizes, int n_in,
                              void* d_out, int out_size, void* d_ws, size_t ws_size,
                              hipStream_t stream) {
    const float* x     = (const float*)d_in[0];
    const float* w_qkv = (const float*)d_in[1];
    const float* w_out = (const float*)d_in[2];
    const float* b_out = (const float*)d_in[3];
    float* out = (float*)d_out;

    char* ws = (char*)d_ws;
    float2* cs = (float2*)ws;                               // 512KB
    u16* xb   = (u16*)(ws + 524288);                        // 8MB
    u16* wqb  = (u16*)(ws + 524288 + 8388608);              // 6MB
    u16* wob  = (u16*)(ws + 524288 + 8388608 + 6291456);    // 2MB
    u16* qb   = (u16*)(ws + 17301504);                      // 8MB
    u16* kb   = (u16*)(ws + 25690112);                      // 8MB
    u16* vt   = (u16*)(ws + 34078720);                      // 8MB
    u16* attb = (u16*)(ws + 42467328);                      // 8MB

    tab_k<<<256, 256, 0, stream>>>(cs);
    cvt_k<<<8192, 256, 0, stream>>>((const float4*)x, (const float4*)w_qkv,
                                    (const float4*)w_out, (uint2*)xb, (uint2*)wqb, (uint2*)wob);
    qkv_mfma_k<<<dim3(24, 32), 256, 0, stream>>>(xb, wqb, cs, qb, kb, vt);
    flash_mfma_k<<<dim3(32, 32), 256, 0, stream>>>(qb, kb, vt, attb);
    proj_mfma_k<<<dim3(8, 32), 256, 0, stream>>>(attb, wob, b_out, out);
}

// Round 7
// 204.461 us; speedup vs baseline: 5.5451x; 1.0955x over previous
//
#include <hip/hip_runtime.h>
#include <math.h>

namespace {

typedef __attribute__((ext_vector_type(8))) short s16x8;
typedef __attribute__((ext_vector_type(4))) float f32x4;
typedef unsigned int u32;
typedef unsigned short u16;

constexpr int B_ = 2;
constexpr int T_ = 2048;
constexpr int C_ = 1024;
constexpr int H_ = 16;
constexpr float L2E = 1.44269504088896340736f;

__device__ inline u16 f2bf(float x) {
    __bf16 h = (__bf16)x;
    return __builtin_bit_cast(u16, h);
}
__device__ inline u32 packbf2(float a, float b) {
    return (u32)f2bf(a) | ((u32)f2bf(b) << 16);
}
__device__ inline void gload_lds16(const void* g, void* lds) {
    __builtin_amdgcn_global_load_lds(
        (const __attribute__((address_space(1))) unsigned int*)g,
        (__attribute__((address_space(3))) unsigned int*)lds, 16, 0, 0);
}

// fence helpers: "memory" clobber pins compiler ordering; raw s_barrier has
// no implied waitcnt, so each wave drains its own counters explicitly.
#define VMW(n) asm volatile("s_waitcnt vmcnt(" #n ")" ::: "memory")
#define LGW0() asm volatile("s_waitcnt lgkmcnt(0)" ::: "memory")
#define BARRIER() do { __builtin_amdgcn_s_barrier(); asm volatile("" ::: "memory"); } while (0)

// ---------------------------------------------------------------- RoPE table
__global__ __launch_bounds__(256) void tab_k(float2* __restrict__ cs) {
    int idx = blockIdx.x * 256 + threadIdx.x;   // 65536
    int t = idx >> 5, i = idx & 31;
    float inv = 1.0f / powf(10000.0f, (float)i / 32.0f);
    float ang = (float)t * inv;
    cs[idx] = make_float2(cosf(ang), sinf(ang));
}

// ---------------------------------------------------------------- f32 -> bf16 convert
__global__ __launch_bounds__(256)
void cvt_k(const float4* __restrict__ x, const float4* __restrict__ wq,
           const float4* __restrict__ wo, uint2* __restrict__ xb,
           uint2* __restrict__ wqb, uint2* __restrict__ wob) {
    int i = blockIdx.x * 256 + threadIdx.x;   // 2097152 total
    const float4* s;
    uint2* d;
    int j;
    if (i < 1048576) { s = x; d = xb; j = i; }
    else if (i < 1048576 + 786432) { s = wq; d = wqb; j = i - 1048576; }
    else { s = wo; d = wob; j = i - (1048576 + 786432); }
    float4 v = s[j];
    d[j] = make_uint2(packbf2(v.x, v.y), packbf2(v.z, v.w));
}

// ---------------------------------------------------------------- QKV MFMA GEMM + RoPE
// 128x128 tile, BK=32, 3-buffer 2-deep prefetch with COUNTED vmcnt (T4):
// stage(t) issued at t-2; per step: vmcnt(4) retires tile t only (tile t+1
// stays in flight across the barrier); stage(t+2); compute(t); lgkmcnt(0).
__global__ __launch_bounds__(256)
void qkv_mfma_k(const u16* __restrict__ xb, const u16* __restrict__ wqb,
                const float2* __restrict__ cs, u16* __restrict__ qb,
                u16* __restrict__ kb, u16* __restrict__ vt) {
    __shared__ char lds[49152];       // 3 bufs x (A 8K | B 8K)
    char* const b0 = lds;
    char* const b1 = lds + 16384;
    char* const b2 = lds + 32768;
    const int tid = threadIdx.x;
    const int w = tid >> 6, lane = tid & 63;
    const int c = lane & 15, g = lane >> 4;
    const int n0 = blockIdx.x * 128, m0 = blockIdx.y * 128;
    const int wr = w >> 1, wc = w & 1;

    f32x4 acc[4][4];
#pragma unroll
    for (int i = 0; i < 4; ++i)
#pragma unroll
        for (int j = 0; j < 4; ++j) acc[i][j] = (f32x4){0.f, 0.f, 0.f, 0.f};

    const u16* Ab = xb + (size_t)m0 * C_;
    const u16* Bb = wqb + (size_t)n0 * C_;
    const int srow = tid >> 2, sslot = tid & 3;

    auto stage = [&](int t, char* base) {
        int k0 = t * 32;
#pragma unroll
        for (int call = 0; call < 2; ++call) {
            int r = call * 64 + srow;
            int ds = sslot ^ ((r >> 1) & 3);
            gload_lds16(Ab + (size_t)r * C_ + k0 + ds * 8, base + call * 4096 + w * 1024);
            gload_lds16(Bb + (size_t)r * C_ + k0 + ds * 8, base + 8192 + call * 4096 + w * 1024);
        }
    };
    auto compute = [&](const char* base) {
        s16x8 aF[4], bF[4];
#pragma unroll
        for (int mf = 0; mf < 4; ++mf) {
            int row = wr * 64 + mf * 16 + c;
            aF[mf] = *(const s16x8*)(base + row * 64 + ((g ^ ((row >> 1) & 3)) * 16));
        }
#pragma unroll
        for (int nf = 0; nf < 4; ++nf) {
            int row = wc * 64 + nf * 16 + c;
            bF[nf] = *(const s16x8*)(base + 8192 + row * 64 + ((g ^ ((row >> 1) & 3)) * 16));
        }
#pragma unroll
        for (int mf = 0; mf < 4; ++mf)
#pragma unroll
            for (int nf = 0; nf < 4; ++nf)
                acc[mf][nf] = __builtin_amdgcn_mfma_f32_16x16x32_bf16(aF[mf], bF[nf], acc[mf][nf], 0, 0, 0);
    };

    stage(0, b0);
    stage(1, b1);
#pragma unroll 1
    for (int t = 0; t < 30; t += 3) {
        VMW(4); BARRIER(); stage(t + 2, b2); compute(b0); LGW0();
        VMW(4); BARRIER(); stage(t + 3, b0); compute(b1); LGW0();
        VMW(4); BARRIER(); stage(t + 4, b1); compute(b2); LGW0();
    }
    VMW(4); BARRIER(); compute(b0); LGW0();   // t = 30
    VMW(0); BARRIER(); compute(b1);           // t = 31

    // epilogue
    const int sec = n0 >> 10;
    const int h = ((n0 & 1023) >> 6) + wc;
    const int b = m0 >> 11;
    const int t0w = (m0 & 2047) + wr * 64;
    const int bh = b * H_ + h;
    if (sec < 2) {
        u16* dst = (sec == 0) ? qb : kb;
        const float qs = (sec == 0) ? 0.125f : 1.0f;
#pragma unroll
        for (int nf = 0; nf < 4; ++nf) {
            int d = nf * 16 + c;
            int ibase = nf * 8 + (c >> 1);
#pragma unroll
            for (int mf = 0; mf < 4; ++mf) {
#pragma unroll
                for (int r = 0; r < 4; ++r) {
                    int t = t0w + mf * 16 + g * 4 + r;
                    float own = acc[mf][nf][r];
                    float partner = __shfl_xor(own, 1);
                    float2 csv = cs[t * 32 + ibase];
                    float rot = (d & 1) ? (own * csv.x + partner * csv.y)
                                        : (own * csv.x - partner * csv.y);
                    rot *= qs;
                    float rothi = __shfl_xor(rot, 1);
                    if (!(d & 1))
                        *(u32*)(dst + ((size_t)bh * T_ + t) * 64 + d) = packbf2(rot, rothi);
                }
            }
        }
    } else {
#pragma unroll
        for (int nf = 0; nf < 4; ++nf) {
            int d = nf * 16 + c;
#pragma unroll
            for (int mf = 0; mf < 4; ++mf) {
                int tb = t0w + mf * 16 + g * 4;
                u32 lo = packbf2(acc[mf][nf][0], acc[mf][nf][1]);
                u32 hi = packbf2(acc[mf][nf][2], acc[mf][nf][3]);
                *(uint2*)(vt + ((size_t)bh * 64 + d) * T_ + tb) = make_uint2(lo, hi);
            }
        }
    }
}

// ---------------------------------------------------------------- flash attention (bf16 MFMA)
// 64 q-rows per block, 4 waves x 16 rows; KV tiles of 64; descending-work
// dispatch (qi = 31 - blockIdx.y) for load balance; 32KB LDS -> 5 blocks/CU.
__global__ __launch_bounds__(256)
void flash_mfma_k(const u16* __restrict__ qb, const u16* __restrict__ kb,
                  const u16* __restrict__ vt, u16* __restrict__ attb) {
    __shared__ char lds[32768];
    char* Qs = lds;                // 8KB: 64 rows x 128B, swz ^((row&7)<<4)
    char* Ks = lds + 8192;         // 8KB
    char* Vs = lds + 16384;        // 8KB: V^T tile (rows = d)
    char* Ps = lds + 24576;        // 8KB: per-wave 2KB, 16 rows x 128B
    const int tid = threadIdx.x, w = tid >> 6, lane = tid & 63;
    const int c = lane & 15, g = lane >> 4;
    const int bh = blockIdx.x;
    const int qi = 31 - blockIdx.y;          // heavy tiles dispatch first
    const int q0 = qi * 64, q0w = q0 + w * 16;
    const u16* Qg = qb + ((size_t)bh * T_ + q0) * 64;
    const u16* Kg = kb + (size_t)bh * T_ * 64;
    const u16* Vg = vt + (size_t)bh * 64 * T_;

    // stage Q (8KB, swizzled source)
#pragma unroll
    for (int call = 0; call < 2; ++call) {
        int row = call * 32 + (tid >> 3);
        int ds = (tid & 7) ^ (row & 7);
        gload_lds16(Qg + (size_t)row * 64 + ds * 8, Qs + call * 4096 + w * 1024);
    }
    __syncthreads();

    s16x8 bQ[2];
#pragma unroll
    for (int kc = 0; kc < 2; ++kc) {
        int row = w * 16 + c;
        bQ[kc] = *(const s16x8*)(Qs + row * 128 + (((kc * 4 + g) ^ (row & 7)) * 16));
    }

    float m_ = -INFINITY, l_ = 0.f;
    f32x4 accO[4];
#pragma unroll
    for (int j = 0; j < 4; ++j) accO[j] = (f32x4){0.f, 0.f, 0.f, 0.f};

    const int nt = qi + 1;
    for (int kt = 0; kt < nt; ++kt) {
        __syncthreads();
        {
            int row = tid >> 3, slot = tid & 7;
#pragma unroll
            for (int call = 0; call < 2; ++call) {
                int r = call * 32 + row;
                int ds = slot ^ (r & 7);
                gload_lds16(Kg + (size_t)(kt * 64 + r) * 64 + ds * 8, Ks + call * 4096 + w * 1024);
                gload_lds16(Vg + (size_t)r * T_ + kt * 64 + ds * 8, Vs + call * 4096 + w * 1024);
            }
        }
        __syncthreads();

        // S^T = K . Q^T   (row=kv=(g*4+r)+16mf, col=qrow=c)
        f32x4 S[4];
#pragma unroll
        for (int mf = 0; mf < 4; ++mf) S[mf] = (f32x4){0.f, 0.f, 0.f, 0.f};
        s16x8 aK[4][2];
#pragma unroll
        for (int mf = 0; mf < 4; ++mf)
#pragma unroll
            for (int kc = 0; kc < 2; ++kc) {
                int row = mf * 16 + c;
                aK[mf][kc] = *(const s16x8*)(Ks + row * 128 + (((kc * 4 + g) ^ (row & 7)) * 16));
            }
#pragma unroll
        for (int kc = 0; kc < 2; ++kc)
#pragma unroll
            for (int mf = 0; mf < 4; ++mf)
                S[mf] = __builtin_amdgcn_mfma_f32_16x16x32_bf16(aK[mf][kc], bQ[kc], S[mf], 0, 0, 0);

        // causal mask (only the diagonal tile needs it)
        if (kt == qi) {
#pragma unroll
            for (int mf = 0; mf < 4; ++mf)
#pragma unroll
                for (int r = 0; r < 4; ++r) {
                    int kvg = kt * 64 + mf * 16 + g * 4 + r;
                    if (kvg > q0w + c) S[mf][r] = -INFINITY;
                }
        }

        // online softmax (q pre-scaled by 0.125); defer-max (skip rescale)
        float mx = -INFINITY;
#pragma unroll
        for (int mf = 0; mf < 4; ++mf)
#pragma unroll
            for (int r = 0; r < 4; ++r) mx = fmaxf(mx, S[mf][r]);
        mx = fmaxf(mx, __shfl_xor(mx, 16));
        mx = fmaxf(mx, __shfl_xor(mx, 32));
        float alpha = 1.0f;
        if (!__all(mx - m_ <= 8.0f)) {
            float mnew = fmaxf(m_, mx);
            alpha = exp2f((m_ - mnew) * L2E);
            m_ = mnew;
#pragma unroll
            for (int r = 0; r < 4; ++r) {
                float ar = __shfl(alpha, g * 4 + r);
#pragma unroll
                for (int nd = 0; nd < 4; ++nd) accO[nd][r] *= ar;
            }
        }
        float sum = 0.f;
#pragma unroll
        for (int mf = 0; mf < 4; ++mf)
#pragma unroll
            for (int r = 0; r < 4; ++r) {
                float p = exp2f((S[mf][r] - m_) * L2E);
                S[mf][r] = p;
                sum += p;
            }
        sum += __shfl_xor(sum, 16);
        sum += __shfl_xor(sum, 32);
        l_ = l_ * alpha + sum;

        // P -> LDS (P[qrow=c][kv], swizzled)
#pragma unroll
        for (int mf = 0; mf < 4; ++mf)
#pragma unroll
            for (int p2 = 0; p2 < 2; ++p2) {
                u32 v = packbf2(S[mf][2 * p2], S[mf][2 * p2 + 1]);
                int off = (mf * 16 + g * 4 + p2 * 2) * 2;
                *(u32*)(Ps + w * 2048 + c * 128 + (off ^ ((c & 7) << 4))) = v;
            }
        // order u32 P-stores before s16x8 P-loads (TBAA hoist hazard)
        __threadfence_block();

        // PV: O += P . V
        s16x8 aP[2], bV[4][2];
#pragma unroll
        for (int kc = 0; kc < 2; ++kc)
            aP[kc] = *(const s16x8*)(Ps + w * 2048 + c * 128 + (((kc * 4 + g) ^ (c & 7)) * 16));
#pragma unroll
        for (int nd = 0; nd < 4; ++nd)
#pragma unroll
            for (int kc = 0; kc < 2; ++kc) {
                int row = nd * 16 + c;
                bV[nd][kc] = *(const s16x8*)(Vs + row * 128 + (((kc * 4 + g) ^ (row & 7)) * 16));
            }
#pragma unroll
        for (int kc = 0; kc < 2; ++kc)
#pragma unroll
            for (int nd = 0; nd < 4; ++nd)
                accO[nd] = __builtin_amdgcn_mfma_f32_16x16x32_bf16(aP[kc], bV[nd][kc], accO[nd], 0, 0, 0);
    }

    // epilogue: attb[b*T + t][h*64 + d]
    const int hh = bh & 15;
    const int bb = bh >> 4;
#pragma unroll
    for (int r = 0; r < 4; ++r) {
        float linv = 1.0f / __shfl(l_, g * 4 + r);
        int t = q0w + g * 4 + r;
        size_t rowb = ((size_t)bb * T_ + t) * C_ + hh * 64;
#pragma unroll
        for (int nd = 0; nd < 4; ++nd)
            attb[rowb + nd * 16 + c] = f2bf(accO[nd][r] * linv);
    }
}

// ---------------------------------------------------------------- out-proj MFMA GEMM + bias
// same 3-buffer counted-vmcnt structure as qkv_mfma_k
__global__ __launch_bounds__(256)
void proj_mfma_k(const u16* __restrict__ attb, const u16* __restrict__ wob,
                 const float* __restrict__ bias, float* __restrict__ out) {
    __shared__ char lds[49152];
    char* const b0 = lds;
    char* const b1 = lds + 16384;
    char* const b2 = lds + 32768;
    const int tid = threadIdx.x;
    const int w = tid >> 6, lane = tid & 63;
    const int c = lane & 15, g = lane >> 4;
    const int n0 = blockIdx.x * 128, m0 = blockIdx.y * 128;
    const int wr = w >> 1, wc = w & 1;

    f32x4 acc[4][4];
#pragma unroll
    for (int i = 0; i < 4; ++i)
#pragma unroll
        for (int j = 0; j < 4; ++j) acc[i][j] = (f32x4){0.f, 0.f, 0.f, 0.f};

    const u16* Ab = attb + (size_t)m0 * C_;
    const u16* Bb = wob + (size_t)n0 * C_;
    const int srow = tid >> 2, sslot = tid & 3;

    auto stage = [&](int t, char* base) {
        int k0 = t * 32;
#pragma unroll
        for (int call = 0; call < 2; ++call) {
            int r = call * 64 + srow;
            int ds = sslot ^ ((r >> 1) & 3);
            gload_lds16(Ab + (size_t)r * C_ + k0 + ds * 8, base + call * 4096 + w * 1024);
            gload_lds16(Bb + (size_t)r * C_ + k0 + ds * 8, base + 8192 + call * 4096 + w * 1024);
        }
    };
    auto compute = [&](const char* base) {
        s16x8 aF[4], bF[4];
#pragma unroll
        for (int mf = 0; mf < 4; ++mf) {
            int row = wr * 64 + mf * 16 + c;
            aF[mf] = *(const s16x8*)(base + row * 64 + ((g ^ ((row >> 1) & 3)) * 16));
        }
#pragma unroll
        for (int nf = 0; nf < 4; ++nf) {
            int row = wc * 64 + nf * 16 + c;
            bF[nf] = *(const s16x8*)(base + 8192 + row * 64 + ((g ^ ((row >> 1) & 3)) * 16));
        }
#pragma unroll
        for (int mf = 0; mf < 4; ++mf)
#pragma unroll
            for (int nf = 0; nf < 4; ++nf)
                acc[mf][nf] = __builtin_amdgcn_mfma_f32_16x16x32_bf16(aF[mf], bF[nf], acc[mf][nf], 0, 0, 0);
    };

    stage(0, b0);
    stage(1, b1);
#pragma unroll 1
    for (int t = 0; t < 30; t += 3) {
        VMW(4); BARRIER(); stage(t + 2, b2); compute(b0); LGW0();
        VMW(4); BARRIER(); stage(t + 3, b0); compute(b1); LGW0();
        VMW(4); BARRIER(); stage(t + 4, b1); compute(b2); LGW0();
    }
    VMW(4); BARRIER(); compute(b0); LGW0();   // t = 30
    VMW(0); BARRIER(); compute(b1);           // t = 31

#pragma unroll
    for (int nf = 0; nf < 4; ++nf) {
        int n = n0 + wc * 64 + nf * 16 + c;
        float bv = bias[n];
#pragma unroll
        for (int mf = 0; mf < 4; ++mf)
#pragma unroll
            for (int r = 0; r < 4; ++r) {
                int mrow = m0 + wr * 64 + mf * 16 + g * 4 + r;
                out[(size_t)mrow * C_ + n] = acc[mf][nf][r] + bv;
            }
    }
}

} // namespace

extern "C" void kernel_launch(void* const* d_in, const int* in_sizes, int n_in,
                              void* d_out, int out_size, void* d_ws, size_t ws_size,
                              hipStream_t stream) {
    const float* x     = (const float*)d_in[0];
    const float* w_qkv = (const float*)d_in[1];
    const float* w_out = (const float*)d_in[2];
    const float* b_out = (const float*)d_in[3];
    float* out = (float*)d_out;

    char* ws = (char*)d_ws;
    float2* cs = (float2*)ws;                               // 512KB
    u16* xb   = (u16*)(ws + 524288);                        // 8MB
    u16* wqb  = (u16*)(ws + 524288 + 8388608);              // 6MB
    u16* wob  = (u16*)(ws + 524288 + 8388608 + 6291456);    // 2MB
    u16* qb   = (u16*)(ws + 17301504);                      // 8MB
    u16* kb   = (u16*)(ws + 25690112);                      // 8MB
    u16* vt   = (u16*)(ws + 34078720);                      // 8MB
    u16* attb = (u16*)(ws + 42467328);                      // 8MB

    tab_k<<<256, 256, 0, stream>>>(cs);
    cvt_k<<<8192, 256, 0, stream>>>((const float4*)x, (const float4*)w_qkv,
                                    (const float4*)w_out, (uint2*)xb, (uint2*)wqb, (uint2*)wob);
    qkv_mfma_k<<<dim3(24, 32), 256, 0, stream>>>(xb, wqb, cs, qb, kb, vt);
    flash_mfma_k<<<dim3(32, 32), 256, 0, stream>>>(qb, kb, vt, attb);
    proj_mfma_k<<<dim3(8, 32), 256, 0, stream>>>(attb, wob, b_out, out);
}